// Round 1
// 417.755 us; speedup vs baseline: 1.0382x; 1.0382x over previous
//
#include <hip/hip_runtime.h>

// EMA over frames: y[n] = w*x[n] + (1-w)*y[n-1], y[-1] = initial_state.
// input (16,8,256,2048) fp32 -> 32768 sequences x 2048 frames, frames contiguous.
//
// One wave per sequence, 4 waves (4 sequences) per 256-thread block.
// Coalesced ownership: lane i holds float4 i of each 1-KiB chunk, i.e. frames
// 256k + 4i .. 4i+3 (4 CONSECUTIVE frames -> a valid segment transform).
// Decay a = 1-w is wave-uniform, so segment decay a^4 is uniform: the wave
// scan needs no A-component. Kogge-Stone on b with uniform multipliers
// a^(4d): 1 shuffle + 1 FMA per step, 6 steps, 8 independent chunk scans.
//
// This revision (vs 433 us version):
//  * nontemporal loads/stores: pure single-touch stream (512 MiB total),
//    zero reuse -> don't let stores write-allocate and evict inbound input
//    lines from L2/L3.
//  * DS-free store phase: chunk totals hoisted via v_readlane (uniform ->
//    SGPR), exclusive-shuffles batched back-to-back, carry chain resolved
//    as 8 scalar-operand FMAs BEFORE any store. Previously each store
//    waited on a ~120-cycle ds_bpermute in the carry chain.

#define N_FRAMES 2048
#define CHUNKS 8           // 2048 / (64 lanes * 4)
#define SEQ_PER_BLOCK 4

typedef float f4v __attribute__((ext_vector_type(4)));

__global__ __launch_bounds__(256) void ema_scan_kernel(
    const float* __restrict__ x,
    const float* __restrict__ y0,
    const float* __restrict__ wgt,
    float* __restrict__ out) {
  const int lane = threadIdx.x & 63;
  const int wid  = threadIdx.x >> 6;
  const int s = blockIdx.x * SEQ_PER_BLOCK + wid;   // sequence id

  const float w_raw = wgt[s & 2047];                // (res,bin) broadcast over batch
  const float w = fminf(fmaxf(w_raw, 0.0f), 1.0f);
  const float a = 1.0f - w;

  // uniform powers of a
  const float a4   = (a * a) * (a * a);  // per-segment decay
  const float A1   = a4;                 // a^4
  const float A2   = A1 * A1;            // a^8
  const float A4   = A2 * A2;            // a^16
  const float A8   = A4 * A4;            // a^32
  const float A16  = A8 * A8;            // a^64
  const float A32  = A16 * A16;          // a^128
  const float a256 = A32 * A32;          // per-chunk decay

  // per-lane power a^(4*lane) via bit-select (works for a == 0 too)
  float powl = 1.0f;
  powl *= (lane & 1)  ? A1  : 1.0f;
  powl *= (lane & 2)  ? A2  : 1.0f;
  powl *= (lane & 4)  ? A4  : 1.0f;
  powl *= (lane & 8)  ? A8  : 1.0f;
  powl *= (lane & 16) ? A16 : 1.0f;
  powl *= (lane & 32) ? A32 : 1.0f;

  const f4v* in4 = reinterpret_cast<const f4v*>(x + (size_t)s * N_FRAMES);
  f4v*       o4  = reinterpret_cast<f4v*>(out + (size_t)s * N_FRAMES);

  // coalesced nontemporal loads: per instruction the wave covers 1 KiB contiguous
  f4v v[CHUNKS];
#pragma unroll
  for (int k = 0; k < CHUNKS; ++k)
    v[k] = __builtin_nontemporal_load(&in4[k * 64 + lane]);

  // local 4-frame segment result applied to zero incoming state
  float b[CHUNKS];
#pragma unroll
  for (int k = 0; k < CHUNKS; ++k) {
    float t = w * v[k].x;
    t = fmaf(a, t, w * v[k].y);
    t = fmaf(a, t, w * v[k].z);
    t = fmaf(a, t, w * v[k].w);
    b[k] = t;
  }

  // inclusive wave scans (independent across chunks -> ILP hides shuffle latency)
#pragma unroll
  for (int k = 0; k < CHUNKS; ++k) {
    float t = b[k];
    float p;
    p = __shfl_up(t, 1, 64);  if (lane >= 1)  t = fmaf(A1,  p, t);
    p = __shfl_up(t, 2, 64);  if (lane >= 2)  t = fmaf(A2,  p, t);
    p = __shfl_up(t, 4, 64);  if (lane >= 4)  t = fmaf(A4,  p, t);
    p = __shfl_up(t, 8, 64);  if (lane >= 8)  t = fmaf(A8,  p, t);
    p = __shfl_up(t, 16, 64); if (lane >= 16) t = fmaf(A16, p, t);
    p = __shfl_up(t, 32, 64); if (lane >= 32) t = fmaf(A32, p, t);
    b[k] = t;
  }

  // chunk totals -> SGPRs (readlane is uniform, ignores nothing here: all
  // lanes active). 8 independent ops, no DS pipe involvement.
  float btot[CHUNKS];
#pragma unroll
  for (int k = 0; k < CHUNKS; ++k)
    btot[k] = __int_as_float(__builtin_amdgcn_readlane(__float_as_int(b[k]), 63));

  // exclusive prefix within each chunk: 8 ds_bpermutes issued back-to-back,
  // latency overlapped across the 8 independent shuffles.
  float excl[CHUNKS];
#pragma unroll
  for (int k = 0; k < CHUNKS; ++k) {
    float e = __shfl_up(b[k], 1, 64);
    excl[k] = (lane == 0) ? 0.0f : e;
  }

  // resolve the whole cross-chunk carry chain up front (8 dependent FMAs,
  // scalar operands -- ~4 cyc each, trivially hidden)
  float cin[CHUNKS];
  float carry = y0[s];
#pragma unroll
  for (int k = 0; k < CHUNKS; ++k) {
    cin[k] = carry;
    carry = fmaf(a256, carry, btot[k]);
  }

  // store phase: no DS ops, no cross-chunk dependence -> 8 stores stream out
#pragma unroll
  for (int k = 0; k < CHUNKS; ++k) {
    float y = fmaf(powl, cin[k], excl[k]);   // state entering this lane's segment
    f4v r;
    y = fmaf(a, y, w * v[k].x); r.x = y;
    y = fmaf(a, y, w * v[k].y); r.y = y;
    y = fmaf(a, y, w * v[k].z); r.z = y;
    y = fmaf(a, y, w * v[k].w); r.w = y;
    __builtin_nontemporal_store(r, &o4[k * 64 + lane]);
  }
}

extern "C" void kernel_launch(void* const* d_in, const int* in_sizes, int n_in,
                              void* d_out, int out_size, void* d_ws, size_t ws_size,
                              hipStream_t stream) {
  const float* x   = (const float*)d_in[0];  // (16,8,256,2048)
  const float* y0  = (const float*)d_in[1];  // (16,8,256)
  const float* wgt = (const float*)d_in[2];  // (8,256)
  float* out = (float*)d_out;

  const int n_seq = 16 * 8 * 256;            // 32768
  ema_scan_kernel<<<dim3(n_seq / SEQ_PER_BLOCK), dim3(256), 0, stream>>>(x, y0, wgt, out);
}